// Round 2
// baseline (240.858 us; speedup 1.0000x reference)
//
#include <hip/hip_runtime.h>

// Laplacian3D, z-marching register-ring version.
// out[b,c,z,y,w] = sum_{i,d in {1,2,4}} k_i[c] * lap_d(x),  k_i = 0.25*sigmoid(p[i][c])
// Thread = fixed (b,c,y,w0..w0+3), marches z over a 32-plane chunk with a
// 9-deep float4 ring (z-4..z+4) so all 6 z-taps are register hits.
// Loads per z-step: 1 ring fill + 6 y-taps + 2 w-taps = 9 float4 (was 15).

__device__ __forceinline__ void addin(float* a, float4 v) {
    a[0] += v.x; a[1] += v.y; a[2] += v.z; a[3] += v.w;
}

__global__ __launch_bounds__(256) void lap3d_zmarch(
    const float* __restrict__ x, const float* __restrict__ p,
    float* __restrict__ out)
{
    // grid: 1024 blocks = (2b * 64c * 2zchunk) * 4 yw-subblocks
    const int bcz   = blockIdx.x >> 2;                        // 0..255
    const int inner = ((blockIdx.x & 3) << 8) | threadIdx.x;  // 0..1023
    const int y     = inner >> 4;
    const int w0    = (inner & 15) << 2;
    const int chunk = bcz & 1;
    const int bc    = bcz >> 1;                               // b*64 + c
    const int c     = bc & 63;
    const int z0    = chunk << 5;

    const float* vol  = x   + (size_t)bc * 262144;            // 64^3
    float*       ovol = out + (size_t)bc * 262144;
    const int    yw   = (y << 6) + w0;

    const float k1 = 0.25f / (1.0f + __expf(-p[c]));
    const float k2 = 0.25f / (1.0f + __expf(-p[64 + c]));
    const float k4 = 0.25f / (1.0f + __expf(-p[128 + c]));
    const float km6 = -6.0f * (k1 + k2 + k4);

    const float4 zero = make_float4(0.f, 0.f, 0.f, 0.f);

    auto ldz = [&](int z) -> float4 {
        return ((unsigned)z < 64u) ? *(const float4*)(vol + (z << 12) + yw) : zero;
    };

    // ring: after the shift in iteration z, r_i holds x(z-4+i); r4 = center
    float4 r0 = zero, r1, r2, r3, r4, r5, r6, r7, r8;
    r1 = ldz(z0 - 4); r2 = ldz(z0 - 3); r3 = ldz(z0 - 2); r4 = ldz(z0 - 1);
    r5 = ldz(z0);     r6 = ldz(z0 + 1); r7 = ldz(z0 + 2); r8 = ldz(z0 + 3);

#pragma unroll
    for (int iz = 0; iz < 32; ++iz) {
        const int z = z0 + iz;
        r0 = r1; r1 = r2; r2 = r3; r3 = r4; r4 = r5; r5 = r6; r6 = r7; r7 = r8;
        r8 = ldz(z + 4);

        const float* pz = vol + (z << 12);

        float a1[4], a2[4], a4[4];
        a1[0] = r3.x + r5.x; a1[1] = r3.y + r5.y; a1[2] = r3.z + r5.z; a1[3] = r3.w + r5.w;
        a2[0] = r2.x + r6.x; a2[1] = r2.y + r6.y; a2[2] = r2.z + r6.z; a2[3] = r2.w + r6.w;
        a4[0] = r0.x + r8.x; a4[1] = r0.y + r8.y; a4[2] = r0.z + r8.z; a4[3] = r0.w + r8.w;

        auto ldy = [&](int yy) -> float4 {
            return ((unsigned)yy < 64u) ? *(const float4*)(pz + (yy << 6) + w0) : zero;
        };
        addin(a1, ldy(y - 1)); addin(a1, ldy(y + 1));
        addin(a2, ldy(y - 2)); addin(a2, ldy(y + 2));
        addin(a4, ldy(y - 4)); addin(a4, ldy(y + 4));

        const float* pc = pz + yw;
        const float4 wm = (w0 >= 4)  ? *(const float4*)(pc - 4) : zero;
        const float4 wp = (w0 <= 56) ? *(const float4*)(pc + 4) : zero;
        const float win[12] = {wm.x, wm.y, wm.z, wm.w,
                               r4.x, r4.y, r4.z, r4.w,
                               wp.x, wp.y, wp.z, wp.w};

        float4 o;
        float* op = &o.x;
#pragma unroll
        for (int j = 0; j < 4; ++j) {
            op[j] = km6 * win[4 + j]
                  + k1 * (a1[j] + win[3 + j] + win[5 + j])
                  + k2 * (a2[j] + win[2 + j] + win[6 + j])
                  + k4 * (a4[j] + win[j]     + win[8 + j]);
        }
        *(float4*)(ovol + (z << 12) + yw) = o;
    }
}

extern "C" void kernel_launch(void* const* d_in, const int* in_sizes, int n_in,
                              void* d_out, int out_size, void* d_ws, size_t ws_size,
                              hipStream_t stream) {
    const float* x = (const float*)d_in[0];
    const float* p = (const float*)d_in[1];
    float* out = (float*)d_out;
    lap3d_zmarch<<<1024, 256, 0, stream>>>(x, p, out);
}

// Round 3
// 58.677 us; speedup vs baseline: 4.1048x; 4.1048x over previous
//
#include <hip/hip_runtime.h>

// Laplacian3D via LDS plane-ring + global_load_lds.
// Block = 1024 threads = full 64x64 (y,w) plane; ring of 9 z-planes in LDS.
// Each input byte fetched from HBM exactly once (plus 1.125x z-chunk halo).
// Taps (center + 6z + 6y + 2w = 15 ds_read_b128) all from LDS, conflict-free.

#define NSLOT 9
#define PLANE 4096   // 64*64 floats = 16 KB
#define CHUNK 32

#define GLD(gsrc, ldst) __builtin_amdgcn_global_load_lds(                      \
    (const __attribute__((address_space(1))) unsigned int*)(gsrc),             \
    (__attribute__((address_space(3))) unsigned int*)(ldst), 16, 0, 0)

#define F4E(v, j) ((j) == 0 ? (v).x : (j) == 1 ? (v).y : (j) == 2 ? (v).z : (v).w)

__global__ __launch_bounds__(1024, 4) void lap3d_lds(
    const float* __restrict__ x, const float* __restrict__ p,
    float* __restrict__ out)
{
    __shared__ __align__(16) float lds[NSLOT][PLANE];   // 147456 B

    const int tid   = threadIdx.x;
    const int bc    = blockIdx.x >> 1;        // b*64 + c, 0..127
    const int chunk = blockIdx.x & 1;
    const int z0    = chunk * CHUNK;
    const int c     = bc & 63;

    const float* vol  = x   + (size_t)bc * (64 * PLANE);
    float*       ovol = out + (size_t)bc * (64 * PLANE);

    const int y    = tid >> 4;
    const int w0   = (tid & 15) << 2;
    const int foff = tid << 2;                // = y*64 + w0 (floats)
    const int wbase = (tid >> 6) << 8;        // wave's float base in a plane

    // per-channel coeffs (wave-uniform scalar loads)
    const float k1  = 0.25f / (1.0f + __expf(-p[c]));
    const float k2  = 0.25f / (1.0f + __expf(-p[64 + c]));
    const float k4  = 0.25f / (1.0f + __expf(-p[128 + c]));
    const float km6 = -6.0f * (k1 + k2 + k4);

    // y-tap clamped offsets + masks (z-independent, computed once)
    const int dys[6] = {-4, -2, -1, 1, 2, 4};
    int yoff[6]; float ym[6];
#pragma unroll
    for (int k = 0; k < 6; ++k) {
        const int yy = y + dys[k];
        const bool v = (unsigned)yy < 64u;
        yoff[k] = (v ? yy : y) * 64 + w0;     // clamped: always in-bounds
        ym[k]   = v ? 1.0f : 0.0f;
    }
    // w-tap clamped offsets + masks (quad-aligned: whole quad in or out)
    const bool wmv = (w0 >= 4), wpv = (w0 <= 56);
    const int   wmoff = wmv ? foff - 4 : foff;
    const int   wpoff = wpv ? foff + 4 : foff;
    const float wmm = wmv ? 1.0f : 0.0f, wpm = wpv ? 1.0f : 0.0f;

    // prologue: planes z0-4 .. z0+4 into slots q%9
#pragma unroll
    for (int i = 0; i < 9; ++i) {
        const int q = z0 - 4 + i;
        if (q >= 0 && q < 64)                 // uniform
            GLD(vol + (size_t)q * PLANE + foff, &lds[q % NSLOT][wbase]);
    }
    __syncthreads();

    for (int iz = 0; iz < CHUNK; ++iz) {
        const int z = z0 + iz;
        const float* plz = lds[z % NSLOT];

        // center + w-window (3 reads) from the center plane
        const float4 c4 = *(const float4*)(plz + foff);
        const float4 wm = *(const float4*)(plz + wmoff);
        const float4 wp = *(const float4*)(plz + wpoff);

        // z taps: uniform validity, slot = (z+dz)%9
        auto ldz = [&](int dz) -> float4 {
            const int q = z + dz;
            if ((unsigned)q < 64u) return *(const float4*)(&lds[q % NSLOT][foff]);
            return make_float4(0.f, 0.f, 0.f, 0.f);
        };
        const float4 zm1 = ldz(-1), zp1 = ldz(1);
        const float4 zm2 = ldz(-2), zp2 = ldz(2);
        const float4 zm4 = ldz(-4), zp4 = ldz(4);

        // y taps (clamped addresses; masked in the FMA)
        const float4 ym4t = *(const float4*)(plz + yoff[0]);
        const float4 ym2t = *(const float4*)(plz + yoff[1]);
        const float4 ym1t = *(const float4*)(plz + yoff[2]);
        const float4 yp1t = *(const float4*)(plz + yoff[3]);
        const float4 yp2t = *(const float4*)(plz + yoff[4]);
        const float4 yp4t = *(const float4*)(plz + yoff[5]);

        const float win[12] = {wm.x * wmm, wm.y * wmm, wm.z * wmm, wm.w * wmm,
                               c4.x, c4.y, c4.z, c4.w,
                               wp.x * wpm, wp.y * wpm, wp.z * wpm, wp.w * wpm};

        float4 o;
        float* op = &o.x;
#pragma unroll
        for (int j = 0; j < 4; ++j) {
            const float s1 = F4E(zm1, j) + F4E(zp1, j) + win[3 + j] + win[5 + j]
                           + ym[2] * F4E(ym1t, j) + ym[3] * F4E(yp1t, j);
            const float s2 = F4E(zm2, j) + F4E(zp2, j) + win[2 + j] + win[6 + j]
                           + ym[1] * F4E(ym2t, j) + ym[4] * F4E(yp2t, j);
            const float s4 = F4E(zm4, j) + F4E(zp4, j) + win[j] + win[8 + j]
                           + ym[0] * F4E(ym4t, j) + ym[5] * F4E(yp4t, j);
            op[j] = km6 * win[4 + j] + k1 * s1 + k2 * s2 + k4 * s4;
        }
        *(float4*)(ovol + (size_t)z * PLANE + foff) = o;

        __syncthreads();   // all waves done reading plane z-4's slot

        // prefetch plane z+5 into the freed slot ((z+5)%9 == (z-4)%9)
        const int q = z + 5;
        if (q < 64 && iz < CHUNK - 1)         // uniform
            GLD(vol + (size_t)q * PLANE + foff, &lds[q % NSLOT][wbase]);

        __syncthreads();   // DMA landed before next step's tap reads
    }
}

extern "C" void kernel_launch(void* const* d_in, const int* in_sizes, int n_in,
                              void* d_out, int out_size, void* d_ws, size_t ws_size,
                              hipStream_t stream) {
    const float* x = (const float*)d_in[0];
    const float* p = (const float*)d_in[1];
    float* out = (float*)d_out;
    lap3d_lds<<<256, 1024, 0, stream>>>(x, p, out);
}

// Round 5
// 50.107 us; speedup vs baseline: 4.8069x; 1.1710x over previous
//
#include <hip/hip_runtime.h>

// Laplacian3D via LDS plane-ring + global_load_lds, 10-slot ring.
// Block = 1024 threads = full 64x64 (y,w) plane; ring of 10 z-planes in LDS
// (exactly 160 KiB). Prefetch distance 1: GLD for plane z+5 is issued BEFORE
// step z's compute (its slot (z+5)%10 is disjoint from tap slots z-4..z+4),
// so the barrier's vmcnt(0) drain at end-of-step has the whole compute phase
// overlapping the HBM latency. ONE barrier per z-step (was two).
// Output uses nontemporal stores (native ext_vector_type for the builtin).

#define NSLOT 10
#define PLANE 4096   // 64*64 floats = 16 KB
#define CHUNK 32

typedef float fx4 __attribute__((ext_vector_type(4)));

#define GLD(gsrc, ldst) __builtin_amdgcn_global_load_lds(                      \
    (const __attribute__((address_space(1))) unsigned int*)(gsrc),             \
    (__attribute__((address_space(3))) unsigned int*)(ldst), 16, 0, 0)

#define F4E(v, j) ((j) == 0 ? (v).x : (j) == 1 ? (v).y : (j) == 2 ? (v).z : (v).w)

__global__ __launch_bounds__(1024, 4) void lap3d_lds10(
    const float* __restrict__ x, const float* __restrict__ p,
    float* __restrict__ out)
{
    __shared__ __align__(16) float lds[NSLOT][PLANE];   // 163840 B = 160 KiB

    const int tid   = threadIdx.x;
    const int bc    = blockIdx.x >> 1;        // b*64 + c, 0..127
    const int chunk = blockIdx.x & 1;
    const int z0    = chunk * CHUNK;
    const int c     = bc & 63;

    const float* vol  = x   + (size_t)bc * (64 * PLANE);
    float*       ovol = out + (size_t)bc * (64 * PLANE);

    const int y     = tid >> 4;
    const int w0    = (tid & 15) << 2;
    const int foff  = tid << 2;               // = y*64 + w0 (floats)
    const int wbase = (tid >> 6) << 8;        // wave's float base in a plane

    // per-channel coeffs (wave-uniform scalar loads)
    const float k1  = 0.25f / (1.0f + __expf(-p[c]));
    const float k2  = 0.25f / (1.0f + __expf(-p[64 + c]));
    const float k4  = 0.25f / (1.0f + __expf(-p[128 + c]));
    const float km6 = -6.0f * (k1 + k2 + k4);

    // y-tap clamped offsets + masks (z-independent)
    const int dys[6] = {-4, -2, -1, 1, 2, 4};
    int yoff[6]; float ym[6];
#pragma unroll
    for (int k = 0; k < 6; ++k) {
        const int yy = y + dys[k];
        const bool v = (unsigned)yy < 64u;
        yoff[k] = (v ? yy : y) * 64 + w0;     // clamped: always in-bounds
        ym[k]   = v ? 1.0f : 0.0f;
    }
    // w-tap clamped offsets + masks (quad-aligned: whole quad in or out)
    const bool wmv = (w0 >= 4), wpv = (w0 <= 56);
    const int   wmoff = wmv ? foff - 4 : foff;
    const int   wpoff = wpv ? foff + 4 : foff;
    const float wmm = wmv ? 1.0f : 0.0f, wpm = wpv ? 1.0f : 0.0f;

    // prologue: planes z0-4 .. z0+4 into slots q%10
#pragma unroll
    for (int i = 0; i < 9; ++i) {
        const int q = z0 - 4 + i;
        if (q >= 0 && q < 64)                 // uniform
            GLD(vol + (size_t)q * PLANE + foff, &lds[q % NSLOT][wbase]);
    }
    __syncthreads();

    for (int iz = 0; iz < CHUNK; ++iz) {
        const int z = z0 + iz;

        // prefetch plane z+5 into slot (z+5)%10 — disjoint from all tap
        // slots (z-4..z+4)%10; its previous occupant (z-5) was last read
        // in step z-1, protected by that step's barrier.
        {
            const int q = z + 5;
            if (q < 64 && iz < CHUNK - 1)     // uniform
                GLD(vol + (size_t)q * PLANE + foff, &lds[q % NSLOT][wbase]);
        }

        const float* plz = lds[z % NSLOT];

        // center + w-window from the center plane
        const float4 c4 = *(const float4*)(plz + foff);
        const float4 wm = *(const float4*)(plz + wmoff);
        const float4 wp = *(const float4*)(plz + wpoff);

        // z taps: uniform validity (scalar branch), slot = (z+dz)%10
        auto ldz = [&](int dz) -> float4 {
            const int q = z + dz;
            if ((unsigned)q < 64u) return *(const float4*)(&lds[q % NSLOT][foff]);
            return make_float4(0.f, 0.f, 0.f, 0.f);
        };
        const float4 zm1 = ldz(-1), zp1 = ldz(1);
        const float4 zm2 = ldz(-2), zp2 = ldz(2);
        const float4 zm4 = ldz(-4), zp4 = ldz(4);

        // y taps (clamped addresses; masked in the FMA)
        const float4 ym4t = *(const float4*)(plz + yoff[0]);
        const float4 ym2t = *(const float4*)(plz + yoff[1]);
        const float4 ym1t = *(const float4*)(plz + yoff[2]);
        const float4 yp1t = *(const float4*)(plz + yoff[3]);
        const float4 yp2t = *(const float4*)(plz + yoff[4]);
        const float4 yp4t = *(const float4*)(plz + yoff[5]);

        const float win[12] = {wm.x * wmm, wm.y * wmm, wm.z * wmm, wm.w * wmm,
                               c4.x, c4.y, c4.z, c4.w,
                               wp.x * wpm, wp.y * wpm, wp.z * wpm, wp.w * wpm};

        fx4 o;
#pragma unroll
        for (int j = 0; j < 4; ++j) {
            const float s1 = F4E(zm1, j) + F4E(zp1, j) + win[3 + j] + win[5 + j]
                           + ym[2] * F4E(ym1t, j) + ym[3] * F4E(yp1t, j);
            const float s2 = F4E(zm2, j) + F4E(zp2, j) + win[2 + j] + win[6 + j]
                           + ym[1] * F4E(ym2t, j) + ym[4] * F4E(yp2t, j);
            const float s4 = F4E(zm4, j) + F4E(zp4, j) + win[j] + win[8 + j]
                           + ym[0] * F4E(ym4t, j) + ym[5] * F4E(yp4t, j);
            o[j] = km6 * win[4 + j] + k1 * s1 + k2 * s2 + k4 * s4;
        }
        __builtin_nontemporal_store(o, (fx4*)(ovol + (size_t)z * PLANE + foff));

        __syncthreads();   // drains prefetch (latency hidden under compute)
                           // and releases slot (z-4)%10 for the next prefetch
    }
}

extern "C" void kernel_launch(void* const* d_in, const int* in_sizes, int n_in,
                              void* d_out, int out_size, void* d_ws, size_t ws_size,
                              hipStream_t stream) {
    const float* x = (const float*)d_in[0];
    const float* p = (const float*)d_in[1];
    float* out = (float*)d_out;
    lap3d_lds10<<<256, 1024, 0, stream>>>(x, p, out);
}